// Round 3
// baseline (15134.796 us; speedup 1.0000x reference)
//
#include <hip/hip_runtime.h>

// VectorQuantiser forward, MI355X fp32.
// N=65536 tokens (16x64x64, channel dim 64 strided by 4096), K=1024 codes, D=64.
//
// Round 5: k_scores rebuilt as a register-tiled GEMM. Rounds 2-4 proved the
// thread=token layout unfixable: the allocator refuses to keep zr[64] in
// arch VGPRs (VGPR_Count pinned at 52 through a "+v" pin AND a memory
// clobber), leaving the loop L1/s_load-latency-bound at VALUBusy 44%.
// New shape: block = 64 tokens x 64 codes, thread = 4x4 micro-tile with
// 4-chain accumulators acc[tok][code][k&3] -> the per-(n,k) dot product is
// BIT-IDENTICAL to the passing kernel (chain r sums channels r,4+r,... in
// ascending order; (c0+c1)+(c2+c3); same d formula). Z and E^T staged in LDS
// (rows padded to 68 words -> conflict-free ds_read_b128 in the k-loop).
// ||z||^2 moved to k_norms (same np_pairwise64_sq), stashed in out_zq which
// k_tokens later overwrites. Argmax via packed keys (ord(d)<<32 | ~idx),
// shuffle + LDS combine + global atomicMax — tie semantics unchanged.

// ---- ws layout (bytes) ----
#define WS_ROW   0        // u64 wsrow[65536]  packed (ord(d)<<32)|~k
#define WS_COL   524288   // u64 wscol[1024]   packed (ord(d)<<32)|~n
#define WS_CNT   532480   // u32 counts[1024]
#define WS_LOSS  536576   // double loss_acc
#define WS_EN2   536592   // float en2[1024]
#define WS_BYTES 540688

__device__ __forceinline__ unsigned int f32_ord(float x) {
    unsigned int b = __float_as_uint(x);
    return (b & 0x80000000u) ? ~b : (b | 0x80000000u);
}

// numpy pairwise sum of squares over 64 contiguous values (8 strided chains,
// then ((r0+r1)+(r2+r3))+((r4+r5)+(r6+r7))), fp32, no contraction.
template <typename F>
__device__ __forceinline__ float np_pairwise64_sq(F get) {
    float r[8];
#pragma unroll
    for (int j = 0; j < 8; ++j) {
        float v = get(j);
        r[j] = __fmul_rn(v, v);
    }
#pragma unroll
    for (int i = 8; i < 64; i += 8) {
#pragma unroll
        for (int j = 0; j < 8; ++j) {
            float v = get(i + j);
            r[j] = __fadd_rn(r[j], __fmul_rn(v, v));
        }
    }
    return __fadd_rn(__fadd_rn(__fadd_rn(r[0], r[1]), __fadd_rn(r[2], r[3])),
                     __fadd_rn(__fadd_rn(r[4], r[5]), __fadd_rn(r[6], r[7])));
}

// ---- K0: norms. blocks 0..3 -> en2[1024]; blocks 4..259 -> zn2[65536].
// zn2 lives in out_zq[0..65535] (scratch; k_tokens overwrites it later).
__global__ __launch_bounds__(256) void k_norms(const float* __restrict__ z,
                                               const float* __restrict__ emb,
                                               float* __restrict__ en2,
                                               float* __restrict__ zn2) {
    if (blockIdx.x < 4) {
        int k = blockIdx.x * 256 + threadIdx.x;
        const float* a = emb + (size_t)k * 64;
        en2[k] = np_pairwise64_sq([&](int i) { return a[i]; });
    } else {
        int n  = (blockIdx.x - 4) * 256 + threadIdx.x;
        int b  = n >> 12;
        int hw = n & 4095;
        const float* zp = z + (size_t)b * 262144 + hw;
        zn2[n] = np_pairwise64_sq([&](int i) { return zp[(size_t)i * 4096]; });
    }
}

// ---- K1: scores as register-tiled GEMM + row/col argmax ----
// grid (1024 token-blocks, 16 code-blocks), block 256 = 4 waves.
// Thread (tx=t&15, ty=t>>4): tokens ty*4..+3, codes tx*4..+3, acc[4][4][4].
__global__ __launch_bounds__(256, 4) void k_scores(
    const float* __restrict__ z, const float* __restrict__ emb,
    const float* __restrict__ en2, const float* __restrict__ zn2,
    unsigned long long* __restrict__ wsrow,
    unsigned long long* __restrict__ wscol) {
    const int t   = threadIdx.x;
    const int tx  = t & 15;
    const int ty  = t >> 4;
    const int w   = t >> 6;
    const int n0  = blockIdx.x * 64;
    const int k0  = blockIdx.y * 64;
    const int b   = n0 >> 12;
    const int hw0 = n0 & 4095;   // multiple of 64 -> 16B-aligned float4 base

    __shared__ __align__(16) float zt[64 * 68];   // [ch][tok], pad 68
    __shared__ __align__(16) float et[64 * 68];   // [ch][code], pad 68
    __shared__ unsigned long long kcb[4][64];

    // --- stage z tile: 64 ch x 64 tok, coalesced float4, linear LDS writes ---
    {
        const float4* z4 =
            reinterpret_cast<const float4*>(z + (size_t)b * 262144 + hw0);
#pragma unroll
        for (int it = 0; it < 4; ++it) {
            int f  = it * 256 + t;
            int ch = f >> 4, tq = f & 15;          // 16 f4 per channel row
            *reinterpret_cast<float4*>(&zt[ch * 68 + tq * 4]) =
                z4[(size_t)ch * 1024 + tq];
        }
        // --- stage e tile transposed: read [code][ch] coalesced, write [ch][code]
        const float4* e4 = reinterpret_cast<const float4*>(emb + (size_t)k0 * 64);
#pragma unroll
        for (int it = 0; it < 4; ++it) {
            int g    = it * 256 + t;
            int code = g >> 4, chq = g & 15;
            float4 v = e4[(size_t)code * 16 + chq];
            et[(4 * chq + 0) * 68 + code] = v.x;
            et[(4 * chq + 1) * 68 + code] = v.y;
            et[(4 * chq + 2) * 68 + code] = v.z;
            et[(4 * chq + 3) * 68 + code] = v.w;
        }
    }
    __syncthreads();

    float acc[4][4][4];
#pragma unroll
    for (int i = 0; i < 4; ++i)
#pragma unroll
        for (int j = 0; j < 4; ++j)
#pragma unroll
            for (int r = 0; r < 4; ++r) acc[i][j][r] = 0.0f;

    union F4 { float4 v; float f[4]; };

    // --- k-loop: 16 chunks of 4 channels; 8 ds_read_b128 + 64 FMA each ---
#pragma unroll
    for (int kc = 0; kc < 64; kc += 4) {
        F4 za[4], ea[4];
#pragma unroll
        for (int r = 0; r < 4; ++r) {
            za[r].v = *reinterpret_cast<const float4*>(
                &zt[(kc + r) * 68 + ty * 4]);
            ea[r].v = *reinterpret_cast<const float4*>(
                &et[(kc + r) * 68 + tx * 4]);
        }
#pragma unroll
        for (int r = 0; r < 4; ++r)
#pragma unroll
            for (int i = 0; i < 4; ++i)
#pragma unroll
                for (int j = 0; j < 4; ++j)
                    acc[i][j][r] = fmaf(ea[r].f[j], za[r].f[i], acc[i][j][r]);
    }

    // --- epilogue: d values (bit-identical combine), then argmax keys ---
    float zn2v[4], en2v[4];
#pragma unroll
    for (int i = 0; i < 4; ++i) zn2v[i] = zn2[n0 + ty * 4 + i];
#pragma unroll
    for (int j = 0; j < 4; ++j) en2v[j] = en2[k0 + tx * 4 + j];

    float d16[4][4];
#pragma unroll
    for (int i = 0; i < 4; ++i)
#pragma unroll
        for (int j = 0; j < 4; ++j) {
            float dot = __fadd_rn(__fadd_rn(acc[i][j][0], acc[i][j][1]),
                                  __fadd_rn(acc[i][j][2], acc[i][j][3]));
            d16[i][j] = __fadd_rn(__fsub_rn(-zn2v[i], en2v[j]), 2.0f * dot);
        }

    // row argmax over this block's 64 codes (ties -> smaller k via ~k)
#pragma unroll
    for (int i = 0; i < 4; ++i) {
        unsigned long long bk = 0ull;
#pragma unroll
        for (int j = 0; j < 4; ++j) {
            unsigned long long key =
                ((unsigned long long)f32_ord(d16[i][j]) << 32) |
                (unsigned long long)(unsigned int)(~(unsigned int)(k0 + tx * 4 + j));
            if (key > bk) bk = key;
        }
#pragma unroll
        for (int m = 1; m < 16; m <<= 1) {
            unsigned long long o = __shfl_xor(bk, m, 64);
            if (o > bk) bk = o;
        }
        if (tx == 0) atomicMax(&wsrow[n0 + ty * 4 + i], bk);
    }

    // col argmax over this block's 64 tokens (ties -> smaller n via ~n)
#pragma unroll
    for (int j = 0; j < 4; ++j) {
        unsigned long long bc = 0ull;
#pragma unroll
        for (int i = 0; i < 4; ++i) {
            unsigned long long key =
                ((unsigned long long)f32_ord(d16[i][j]) << 32) |
                (unsigned long long)(unsigned int)(~(unsigned int)(n0 + ty * 4 + i));
            if (key > bc) bc = key;
        }
        { unsigned long long o = __shfl_xor(bc, 16, 64); if (o > bc) bc = o; }
        { unsigned long long o = __shfl_xor(bc, 32, 64); if (o > bc) bc = o; }
        if ((t & 48) == 0) kcb[w][tx * 4 + j] = bc;   // lane<16 of each wave
    }
    __syncthreads();
    if (t < 64) {
        unsigned long long m0 = kcb[0][t];
#pragma unroll
        for (int q = 1; q < 4; ++q) {
            unsigned long long o = kcb[q][t];
            if (o > m0) m0 = o;
        }
        atomicMax(&wscol[k0 + t], m0);
    }
}

// ---- K2: per-token outputs: z_q (straight-through), indices, hist, loss ----
__global__ __launch_bounds__(256) void k_tokens(
    const float* __restrict__ z, const float* __restrict__ emb,
    const unsigned long long* __restrict__ wsrow,
    unsigned int* __restrict__ counts, double* __restrict__ loss_acc,
    float* __restrict__ out_zq, float* __restrict__ out_idx) {
    const int n  = blockIdx.x * 256 + threadIdx.x;
    const int b  = n >> 12;
    const int hw = n & 4095;

    unsigned long long key = wsrow[n];
    int idx = (int)(~(unsigned int)(key & 0xFFFFFFFFull));
    out_idx[n] = (float)idx;
    atomicAdd(&counts[idx], 1u);

    const float* zp = z + (size_t)b * 262144 + hw;
    float*       op = out_zq + (size_t)b * 262144 + hw;
    const float* ep = emb + (size_t)idx * 64;

    double ls = 0.0;
#pragma unroll
    for (int c = 0; c < 64; ++c) {
        float zc   = zp[(size_t)c * 4096];
        float eq   = ep[c];
        float diff = __fsub_rn(eq, zc);              // fl(z_q - zc)
        float sq   = __fmul_rn(diff, diff);
        ls += (double)sq;
        op[(size_t)c * 4096] = __fadd_rn(zc, diff);  // zc + fl(z_q - zc)
    }

    __shared__ double sred[256];
    sred[threadIdx.x] = ls;
    __syncthreads();
    for (int st = 128; st; st >>= 1) {
        if (threadIdx.x < st) sred[threadIdx.x] += sred[threadIdx.x + st];
        __syncthreads();
    }
    if (threadIdx.x == 0) atomicAdd(loss_acc, sred[0]);
}

// ---- K3: tail — new embedding (all blocks) + scalars (block 0 only) ----
__global__ __launch_bounds__(1024) void k_tail(
    const float* __restrict__ z, const float* __restrict__ emb,
    const float* __restrict__ embed_prob,
    const unsigned long long* __restrict__ wscol,
    const unsigned int* __restrict__ counts,
    const double* __restrict__ loss_acc,
    float* __restrict__ out_newemb, float* __restrict__ out_loss,
    float* __restrict__ out_perp, float* __restrict__ out_prob) {
    const int k = blockIdx.x * 16 + (threadIdx.x >> 6);
    const int c = threadIdx.x & 63;

    float avg  = (float)counts[k] * (1.0f / 65536.0f);
    float pnew = __fadd_rn(__fmul_rn(embed_prob[k], 0.99f),
                           __fmul_rn(0.01f, avg));
    float tt = __fdiv_rn(__fmul_rn(__fmul_rn(pnew, 1024.0f), 10.0f), 0.01f);
    float dk = expf(__fsub_rn(-tt, 1e-3f));
    float omd = __fsub_rn(1.0f, dk);

    unsigned long long ck = wscol[k];
    int cn  = (int)(~(unsigned int)(ck & 0xFFFFFFFFull));
    int cb  = cn >> 12;
    int chw = cn & 4095;

    float rf = z[(size_t)cb * 262144 + (size_t)c * 4096 + chw];
    float e  = emb[(size_t)k * 64 + c];
    out_newemb[(size_t)k * 64 + c] =
        __fadd_rn(__fmul_rn(e, omd), __fmul_rn(rf, dk));

    if (blockIdx.x == 0) {
        const int q = threadIdx.x;

        float avg2  = (float)counts[q] * (1.0f / 65536.0f);
        float pnew2 = __fadd_rn(__fmul_rn(embed_prob[q], 0.99f),
                                __fmul_rn(0.01f, avg2));
        out_prob[q] = pnew2;

        float term = __fmul_rn(avg2, logf(__fadd_rn(avg2, 1e-10f)));
        __shared__ double red[1024];
        red[q] = (double)term;
        __syncthreads();
        for (int st = 512; st; st >>= 1) {
            if (q < st) red[q] += red[q + st];
            __syncthreads();
        }
        if (q == 0) {
            float s32 = (float)red[0];
            out_perp[0] = expf(-s32);
            double lm = loss_acc[0] / 4194304.0;
            float  m  = (float)lm;
            out_loss[0] = __fadd_rn(__fmul_rn(0.25f, m), m);  // BETA*m + m
        }
    }
}

extern "C" void kernel_launch(void* const* d_in, const int* in_sizes, int n_in,
                              void* d_out, int out_size, void* d_ws, size_t ws_size,
                              hipStream_t stream) {
    const float* z    = (const float*)d_in[0];   // 16*64*64*64
    const float* emb  = (const float*)d_in[1];   // 1024*64
    const float* prob = (const float*)d_in[2];   // 1024

    float* out        = (float*)d_out;
    float* out_zq     = out;                 // 4194304
    float* out_loss   = out + 4194304;       // 1
    float* out_perp   = out + 4194305;       // 1
    float* out_newemb = out + 4194306;       // 65536
    float* out_prob   = out + 4259842;       // 1024
    float* out_idx    = out + 4260866;       // 65536

    char* ws = (char*)d_ws;
    unsigned long long* wsrow = (unsigned long long*)(ws + WS_ROW);
    unsigned long long* wscol = (unsigned long long*)(ws + WS_COL);
    unsigned int*       cnts  = (unsigned int*)(ws + WS_CNT);
    double*             lacc  = (double*)(ws + WS_LOSS);
    float*              en2   = (float*)(ws + WS_EN2);

    // zn2 scratch = first 65536 floats of out_zq (k_tokens overwrites later)
    float* zn2 = out_zq;

    hipMemsetAsync(d_ws, 0, WS_BYTES, stream);

    hipLaunchKernelGGL(k_norms, dim3(260), dim3(256), 0, stream,
                       z, emb, en2, zn2);
    hipLaunchKernelGGL(k_scores, dim3(1024, 16), dim3(256), 0, stream,
                       z, emb, en2, zn2, wsrow, wscol);
    hipLaunchKernelGGL(k_tokens, dim3(256), dim3(256), 0, stream,
                       z, emb, wsrow, cnts, lacc, out_zq, out_idx);
    hipLaunchKernelGGL(k_tail, dim3(64), dim3(1024), 0, stream,
                       z, emb, prob, wscol, cnts, lacc,
                       out_newemb, out_loss, out_perp, out_prob);
}

// Round 4
// 264.968 us; speedup vs baseline: 57.1194x; 57.1194x over previous
//
#include <hip/hip_runtime.h>

// VectorQuantiser forward, MI355X fp32.
// N=65536 tokens (16x64x64, channel dim 64 strided by 4096), K=1024 codes, D=64.
//
// Round 6: same register-tiled GEMM as round 5, minus the self-inflicted
// spill. Round-5 counters: VGPR_Count=64, 24.6 GB scratch writes, VALU 1.2%
// => __launch_bounds__(256,4) set waves-per-eu=4 -> arch-VGPR cap 256/4=64,
// below the ~112 live registers of the 4x4x4-chain micro-tile. Now
// __launch_bounds__(256,2) (cap 128) + #pragma unroll 1 on the k-loop so the
// scheduler can't hoist loads past the budget. Also fixes the 1.5e7 LDS bank
// conflicts: e-staging now writes lane-consecutive codes (stride-1 rows)
// instead of lane-consecutive channels (stride-272 ≡ 8-way conflicts).
// All rounding-sensitive fp ops bit-identical to the passing round-5 code
// (4-chain acc[tok][code][k&3], (c0+c1)+(c2+c3), same d formula, same keys).

// ---- ws layout (bytes) ----
#define WS_ROW   0        // u64 wsrow[65536]  packed (ord(d)<<32)|~k
#define WS_COL   524288   // u64 wscol[1024]   packed (ord(d)<<32)|~n
#define WS_CNT   532480   // u32 counts[1024]
#define WS_LOSS  536576   // double loss_acc
#define WS_EN2   536592   // float en2[1024]
#define WS_BYTES 540688

__device__ __forceinline__ unsigned int f32_ord(float x) {
    unsigned int b = __float_as_uint(x);
    return (b & 0x80000000u) ? ~b : (b | 0x80000000u);
}

// numpy pairwise sum of squares over 64 contiguous values (8 strided chains,
// then ((r0+r1)+(r2+r3))+((r4+r5)+(r6+r7))), fp32, no contraction.
template <typename F>
__device__ __forceinline__ float np_pairwise64_sq(F get) {
    float r[8];
#pragma unroll
    for (int j = 0; j < 8; ++j) {
        float v = get(j);
        r[j] = __fmul_rn(v, v);
    }
#pragma unroll
    for (int i = 8; i < 64; i += 8) {
#pragma unroll
        for (int j = 0; j < 8; ++j) {
            float v = get(i + j);
            r[j] = __fadd_rn(r[j], __fmul_rn(v, v));
        }
    }
    return __fadd_rn(__fadd_rn(__fadd_rn(r[0], r[1]), __fadd_rn(r[2], r[3])),
                     __fadd_rn(__fadd_rn(r[4], r[5]), __fadd_rn(r[6], r[7])));
}

// ---- K0: norms. blocks 0..3 -> en2[1024]; blocks 4..259 -> zn2[65536].
// zn2 lives in out_zq[0..65535] (scratch; k_tokens overwrites it later).
__global__ __launch_bounds__(256) void k_norms(const float* __restrict__ z,
                                               const float* __restrict__ emb,
                                               float* __restrict__ en2,
                                               float* __restrict__ zn2) {
    if (blockIdx.x < 4) {
        int k = blockIdx.x * 256 + threadIdx.x;
        const float* a = emb + (size_t)k * 64;
        en2[k] = np_pairwise64_sq([&](int i) { return a[i]; });
    } else {
        int n  = (blockIdx.x - 4) * 256 + threadIdx.x;
        int b  = n >> 12;
        int hw = n & 4095;
        const float* zp = z + (size_t)b * 262144 + hw;
        zn2[n] = np_pairwise64_sq([&](int i) { return zp[(size_t)i * 4096]; });
    }
}

// ---- K1: scores as register-tiled GEMM + row/col argmax ----
// grid (1024 token-blocks, 16 code-blocks), block 256 = 4 waves.
// Thread (tx=t&15, ty=t>>4): tokens ty*4..+3, codes tx*4..+3, acc[4][4][4].
__global__ __launch_bounds__(256, 2) void k_scores(
    const float* __restrict__ z, const float* __restrict__ emb,
    const float* __restrict__ en2, const float* __restrict__ zn2,
    unsigned long long* __restrict__ wsrow,
    unsigned long long* __restrict__ wscol) {
    const int t   = threadIdx.x;
    const int tx  = t & 15;
    const int ty  = t >> 4;
    const int w   = t >> 6;
    const int n0  = blockIdx.x * 64;
    const int k0  = blockIdx.y * 64;
    const int b   = n0 >> 12;
    const int hw0 = n0 & 4095;   // multiple of 64 -> 16B-aligned float4 base

    __shared__ __align__(16) float zt[64 * 68];   // [ch][tok], pad 68
    __shared__ __align__(16) float et[64 * 68];   // [ch][code], pad 68
    __shared__ unsigned long long kcb[4][64];

    // --- stage z tile: 64 ch x 64 tok, coalesced float4, conflict-free ---
    {
        const float4* z4 =
            reinterpret_cast<const float4*>(z + (size_t)b * 262144 + hw0);
#pragma unroll
        for (int it = 0; it < 4; ++it) {
            int f  = it * 256 + t;
            int ch = f >> 4, tq = f & 15;          // 16 f4 per channel row
            *reinterpret_cast<float4*>(&zt[ch * 68 + tq * 4]) =
                z4[(size_t)ch * 1024 + tq];
        }
        // --- stage e tile transposed. Lane-consecutive CODE (not channel):
        // LDS store addr = (4*chq+r)*68 + code -> stride-1 across the wave,
        // conflict-free (round-5's chq-major mapping was 8-way, 1.5e7 cyc).
        // Global read strided 1KB/lane, but emb is 256KB L2-resident.
        const float4* e4 = reinterpret_cast<const float4*>(emb + (size_t)k0 * 64);
#pragma unroll
        for (int it = 0; it < 4; ++it) {
            int g    = it * 256 + t;
            int code = g & 63, chq = g >> 6;       // chq = it*4 + (t>>6)
            float4 v = e4[(size_t)code * 16 + chq];
            et[(4 * chq + 0) * 68 + code] = v.x;
            et[(4 * chq + 1) * 68 + code] = v.y;
            et[(4 * chq + 2) * 68 + code] = v.z;
            et[(4 * chq + 3) * 68 + code] = v.w;
        }
    }
    __syncthreads();

    float acc[4][4][4];
#pragma unroll
    for (int i = 0; i < 4; ++i)
#pragma unroll
        for (int j = 0; j < 4; ++j)
#pragma unroll
            for (int r = 0; r < 4; ++r) acc[i][j][r] = 0.0f;

    union F4 { float4 v; float f[4]; };

    // --- k-loop: 16 chunks of 4 channels; 8 ds_read_b128 + 64 FMA each.
    // KEPT ROLLED: full unroll lets the scheduler hoist loads past the
    // 128-VGPR budget (round-5 spill). 16 waves/CU hide the ds_read latency.
#pragma unroll 1
    for (int kc = 0; kc < 64; kc += 4) {
        F4 za[4], ea[4];
#pragma unroll
        for (int r = 0; r < 4; ++r) {
            za[r].v = *reinterpret_cast<const float4*>(
                &zt[(kc + r) * 68 + ty * 4]);
            ea[r].v = *reinterpret_cast<const float4*>(
                &et[(kc + r) * 68 + tx * 4]);
        }
#pragma unroll
        for (int r = 0; r < 4; ++r)
#pragma unroll
            for (int i = 0; i < 4; ++i)
#pragma unroll
                for (int j = 0; j < 4; ++j)
                    acc[i][j][r] = fmaf(ea[r].f[j], za[r].f[i], acc[i][j][r]);
    }

    // --- epilogue: d values (bit-identical combine), then argmax keys ---
    float zn2v[4], en2v[4];
#pragma unroll
    for (int i = 0; i < 4; ++i) zn2v[i] = zn2[n0 + ty * 4 + i];
#pragma unroll
    for (int j = 0; j < 4; ++j) en2v[j] = en2[k0 + tx * 4 + j];

    float d16[4][4];
#pragma unroll
    for (int i = 0; i < 4; ++i)
#pragma unroll
        for (int j = 0; j < 4; ++j) {
            float dot = __fadd_rn(__fadd_rn(acc[i][j][0], acc[i][j][1]),
                                  __fadd_rn(acc[i][j][2], acc[i][j][3]));
            d16[i][j] = __fadd_rn(__fsub_rn(-zn2v[i], en2v[j]), 2.0f * dot);
        }

    // row argmax over this block's 64 codes (ties -> smaller k via ~k)
#pragma unroll
    for (int i = 0; i < 4; ++i) {
        unsigned long long bk = 0ull;
#pragma unroll
        for (int j = 0; j < 4; ++j) {
            unsigned long long key =
                ((unsigned long long)f32_ord(d16[i][j]) << 32) |
                (unsigned long long)(unsigned int)(~(unsigned int)(k0 + tx * 4 + j));
            if (key > bk) bk = key;
        }
#pragma unroll
        for (int m = 1; m < 16; m <<= 1) {
            unsigned long long o = __shfl_xor(bk, m, 64);
            if (o > bk) bk = o;
        }
        if (tx == 0) atomicMax(&wsrow[n0 + ty * 4 + i], bk);
    }

    // col argmax over this block's 64 tokens (ties -> smaller n via ~n)
#pragma unroll
    for (int j = 0; j < 4; ++j) {
        unsigned long long bc = 0ull;
#pragma unroll
        for (int i = 0; i < 4; ++i) {
            unsigned long long key =
                ((unsigned long long)f32_ord(d16[i][j]) << 32) |
                (unsigned long long)(unsigned int)(~(unsigned int)(n0 + ty * 4 + i));
            if (key > bc) bc = key;
        }
        { unsigned long long o = __shfl_xor(bc, 16, 64); if (o > bc) bc = o; }
        { unsigned long long o = __shfl_xor(bc, 32, 64); if (o > bc) bc = o; }
        if ((t & 48) == 0) kcb[w][tx * 4 + j] = bc;   // lane<16 of each wave
    }
    __syncthreads();
    if (t < 64) {
        unsigned long long m0 = kcb[0][t];
#pragma unroll
        for (int q = 1; q < 4; ++q) {
            unsigned long long o = kcb[q][t];
            if (o > m0) m0 = o;
        }
        atomicMax(&wscol[k0 + t], m0);
    }
}

// ---- K2: per-token outputs: z_q (straight-through), indices, hist, loss ----
__global__ __launch_bounds__(256) void k_tokens(
    const float* __restrict__ z, const float* __restrict__ emb,
    const unsigned long long* __restrict__ wsrow,
    unsigned int* __restrict__ counts, double* __restrict__ loss_acc,
    float* __restrict__ out_zq, float* __restrict__ out_idx) {
    const int n  = blockIdx.x * 256 + threadIdx.x;
    const int b  = n >> 12;
    const int hw = n & 4095;

    unsigned long long key = wsrow[n];
    int idx = (int)(~(unsigned int)(key & 0xFFFFFFFFull));
    out_idx[n] = (float)idx;
    atomicAdd(&counts[idx], 1u);

    const float* zp = z + (size_t)b * 262144 + hw;
    float*       op = out_zq + (size_t)b * 262144 + hw;
    const float* ep = emb + (size_t)idx * 64;

    double ls = 0.0;
#pragma unroll
    for (int c = 0; c < 64; ++c) {
        float zc   = zp[(size_t)c * 4096];
        float eq   = ep[c];
        float diff = __fsub_rn(eq, zc);              // fl(z_q - zc)
        float sq   = __fmul_rn(diff, diff);
        ls += (double)sq;
        op[(size_t)c * 4096] = __fadd_rn(zc, diff);  // zc + fl(z_q - zc)
    }

    __shared__ double sred[256];
    sred[threadIdx.x] = ls;
    __syncthreads();
    for (int st = 128; st; st >>= 1) {
        if (threadIdx.x < st) sred[threadIdx.x] += sred[threadIdx.x + st];
        __syncthreads();
    }
    if (threadIdx.x == 0) atomicAdd(loss_acc, sred[0]);
}

// ---- K3: tail — new embedding (all blocks) + scalars (block 0 only) ----
__global__ __launch_bounds__(1024) void k_tail(
    const float* __restrict__ z, const float* __restrict__ emb,
    const float* __restrict__ embed_prob,
    const unsigned long long* __restrict__ wscol,
    const unsigned int* __restrict__ counts,
    const double* __restrict__ loss_acc,
    float* __restrict__ out_newemb, float* __restrict__ out_loss,
    float* __restrict__ out_perp, float* __restrict__ out_prob) {
    const int k = blockIdx.x * 16 + (threadIdx.x >> 6);
    const int c = threadIdx.x & 63;

    float avg  = (float)counts[k] * (1.0f / 65536.0f);
    float pnew = __fadd_rn(__fmul_rn(embed_prob[k], 0.99f),
                           __fmul_rn(0.01f, avg));
    float tt = __fdiv_rn(__fmul_rn(__fmul_rn(pnew, 1024.0f), 10.0f), 0.01f);
    float dk = expf(__fsub_rn(-tt, 1e-3f));
    float omd = __fsub_rn(1.0f, dk);

    unsigned long long ck = wscol[k];
    int cn  = (int)(~(unsigned int)(ck & 0xFFFFFFFFull));
    int cb  = cn >> 12;
    int chw = cn & 4095;

    float rf = z[(size_t)cb * 262144 + (size_t)c * 4096 + chw];
    float e  = emb[(size_t)k * 64 + c];
    out_newemb[(size_t)k * 64 + c] =
        __fadd_rn(__fmul_rn(e, omd), __fmul_rn(rf, dk));

    if (blockIdx.x == 0) {
        const int q = threadIdx.x;

        float avg2  = (float)counts[q] * (1.0f / 65536.0f);
        float pnew2 = __fadd_rn(__fmul_rn(embed_prob[q], 0.99f),
                                __fmul_rn(0.01f, avg2));
        out_prob[q] = pnew2;

        float term = __fmul_rn(avg2, logf(__fadd_rn(avg2, 1e-10f)));
        __shared__ double red[1024];
        red[q] = (double)term;
        __syncthreads();
        for (int st = 512; st; st >>= 1) {
            if (q < st) red[q] += red[q + st];
            __syncthreads();
        }
        if (q == 0) {
            float s32 = (float)red[0];
            out_perp[0] = expf(-s32);
            double lm = loss_acc[0] / 4194304.0;
            float  m  = (float)lm;
            out_loss[0] = __fadd_rn(__fmul_rn(0.25f, m), m);  // BETA*m + m
        }
    }
}

extern "C" void kernel_launch(void* const* d_in, const int* in_sizes, int n_in,
                              void* d_out, int out_size, void* d_ws, size_t ws_size,
                              hipStream_t stream) {
    const float* z    = (const float*)d_in[0];   // 16*64*64*64
    const float* emb  = (const float*)d_in[1];   // 1024*64
    const float* prob = (const float*)d_in[2];   // 1024

    float* out        = (float*)d_out;
    float* out_zq     = out;                 // 4194304
    float* out_loss   = out + 4194304;       // 1
    float* out_perp   = out + 4194305;       // 1
    float* out_newemb = out + 4194306;       // 65536
    float* out_prob   = out + 4259842;       // 1024
    float* out_idx    = out + 4260866;       // 65536

    char* ws = (char*)d_ws;
    unsigned long long* wsrow = (unsigned long long*)(ws + WS_ROW);
    unsigned long long* wscol = (unsigned long long*)(ws + WS_COL);
    unsigned int*       cnts  = (unsigned int*)(ws + WS_CNT);
    double*             lacc  = (double*)(ws + WS_LOSS);
    float*              en2   = (float*)(ws + WS_EN2);

    // zn2 scratch = first 65536 floats of out_zq (k_tokens overwrites later)
    float* zn2 = out_zq;

    hipMemsetAsync(d_ws, 0, WS_BYTES, stream);

    hipLaunchKernelGGL(k_norms, dim3(260), dim3(256), 0, stream,
                       z, emb, en2, zn2);
    hipLaunchKernelGGL(k_scores, dim3(1024, 16), dim3(256), 0, stream,
                       z, emb, en2, zn2, wsrow, wscol);
    hipLaunchKernelGGL(k_tokens, dim3(256), dim3(256), 0, stream,
                       z, emb, wsrow, cnts, lacc, out_zq, out_idx);
    hipLaunchKernelGGL(k_tail, dim3(64), dim3(1024), 0, stream,
                       z, emb, prob, wscol, cnts, lacc,
                       out_newemb, out_loss, out_perp, out_prob);
}